// Round 4
// baseline (2538.419 us; speedup 1.0000x reference)
//
#include <hip/hip_runtime.h>

// GCN critic: 4 layers (128->16->16->16->1), symmetric gcn_norm with self-loops,
// global mean pool. N=100000 nodes, E=6400000 edges.
// R3: bucket sort by dst>>8 (391 buckets x 256 nodes), LDS-private accumulation,
// zero per-edge global atomics.

#define BLK 256
#define BSHIFT 8
#define BSIZE 256            // nodes per bucket
#define NBUCK_MAX 512
#define CAP 18000            // max edges per bucket (mean 16384, sigma ~128; +12 sigma)
#define CSTRIDE 16           // gcnt padded to one 64B line per counter
#define CHUNK 8192           // edges per k_bucket block
#define NSRC_MASK 131071     // 17 bits for src < 131072

static __device__ __forceinline__ float relu_(float v) { return v > 0.f ? v : 0.f; }

// ---- zero bucket counters + out ----
__global__ __launch_bounds__(BLK) void k_zero(int* __restrict__ gcnt, float* __restrict__ out, int ncnt) {
    int i = blockIdx.x * BLK + threadIdx.x;
    if (i < ncnt) gcnt[i] = 0;
    if (i == 0) out[0] = 0.0f;
}

// ---- bucket sort: ep[b*CAP + pos] = {w (hi32), meta = dstloc<<17 | src (lo32)} ----
__global__ __launch_bounds__(BLK) void k_bucket(const int* __restrict__ src, const int* __restrict__ dst,
                                                const float* __restrict__ w, int* __restrict__ gcnt,
                                                long long* __restrict__ ep, int E, int nbuck) {
    __shared__ int hist[NBUCK_MAX];
    __shared__ int cur[NBUCK_MAX];
    const int t = threadIdx.x;
    for (int b = t; b < nbuck; b += BLK) hist[b] = 0;
    __syncthreads();
    const int c0 = blockIdx.x * CHUNK;
    const int c1 = min(c0 + CHUNK, E);
    for (int e = c0 + t; e < c1; e += BLK) {
        atomicAdd(&hist[dst[e] >> BSHIFT], 1);
    }
    __syncthreads();
    for (int b = t; b < nbuck; b += BLK) {
        int h = hist[b];
        cur[b] = h ? atomicAdd(&gcnt[b * CSTRIDE], h) : 0;   // reserve range; cur = running cursor
    }
    __syncthreads();
    for (int e = c0 + t; e < c1; e += BLK) {
        int d = dst[e];
        int b = d >> BSHIFT;
        int pos = atomicAdd(&cur[b], 1);
        if (pos < CAP) {
            unsigned int meta = ((unsigned int)(d & (BSIZE - 1)) << 17) | (unsigned int)src[e];
            long long rec = ((long long)__float_as_int(w[e]) << 32) | (long long)meta;
            ep[(size_t)b * CAP + pos] = rec;
        }
    }
}

// ---- per-bucket degree -> dis = 1/sqrt(deg+1) ----
__global__ __launch_bounds__(BLK) void k_degdis(const long long* __restrict__ ep, const int* __restrict__ gcnt,
                                                float* __restrict__ dis, int n) {
    __shared__ float dl[BSIZE];
    const int b = blockIdx.x, t = threadIdx.x;
    dl[t] = 0.f;
    __syncthreads();
    const int cnt = min(gcnt[b * CSTRIDE], CAP);
    const long long* p = ep + (size_t)b * CAP;
    for (int e = t; e < cnt; e += BLK) {
        long long rec = p[e];
        unsigned int meta = (unsigned int)rec;
        float wv = __int_as_float((int)(rec >> 32));
        atomicAdd(&dl[meta >> 17], wv);
    }
    __syncthreads();
    int node = (b << BSHIFT) + t;
    if (node < n) {
        float dv = dl[t] + 1.0f;   // +1 self-loop
        dis[node] = (float)(1.0 / sqrt((double)dv));
    }
}

// ---- transform w -> norm = dis[src]*w*dis[dst] in place ----
__global__ __launch_bounds__(BLK) void k_norm(long long* __restrict__ ep, const int* __restrict__ gcnt,
                                              const float* __restrict__ dis, int n) {
    __shared__ float dloc[BSIZE];
    const int b = blockIdx.x, t = threadIdx.x;
    int node = (b << BSHIFT) + t;
    dloc[t] = (node < n) ? dis[node] : 0.f;
    __syncthreads();
    const int cnt = min(gcnt[b * CSTRIDE], CAP);
    long long* p = ep + (size_t)b * CAP;
    for (int e = t; e < cnt; e += BLK) {
        long long rec = p[e];
        unsigned int meta = (unsigned int)rec;
        float wv = __int_as_float((int)(rec >> 32));
        float nv = dis[meta & NSRC_MASK] * wv * dloc[meta >> 17];
        p[e] = ((long long)__float_as_int(nv) << 32) | (long long)meta;
    }
}

// ---- dense: z = act(xin) @ W ; act = relu(x + bprev) if RELU ----
template<int FI, int FO, bool RELU>
__global__ __launch_bounds__(BLK) void k_dense(const float* __restrict__ xin, const float* __restrict__ W,
                                               const float* __restrict__ bprev, float* __restrict__ z, int n) {
    constexpr int NPB = BLK / FO;
    constexpr int XP = FI + 1;
    __shared__ float Wl[FI * FO];
    __shared__ float xs[NPB * XP];
    const int t = threadIdx.x;
    for (int i = t; i < FI * FO; i += BLK) Wl[i] = W[i];
    const int node0 = blockIdx.x * NPB;
    for (int i = t; i < NPB * FI; i += BLK) {
        int r = i / FI, c = i - r * FI;
        int node = node0 + r;
        float v = 0.f;
        if (node < n) {
            v = xin[node * FI + c];
            if constexpr (RELU) v = relu_(v + bprev[c]);
        }
        xs[r * XP + c] = v;
    }
    __syncthreads();
    const int r = t / FO, j = t - r * FO;
    const int node = node0 + r;
    if (node < n) {
        float s = 0.f;
#pragma unroll
        for (int k = 0; k < FI; ++k) s += xs[r * XP + k] * Wl[k * FO + j];
        z[node * FO + j] = s;
    }
}

// ---- aggregation FO=16: one block per bucket, LDS accumulator, 16 lanes per edge ----
__global__ __launch_bounds__(1024) void k_agg16(const long long* __restrict__ ep, const int* __restrict__ gcnt,
                                                const float* __restrict__ dis, const float* __restrict__ z,
                                                float* __restrict__ acc, int n) {
    __shared__ float al[BSIZE * 16];   // 16 KB
    const int b = blockIdx.x, t = threadIdx.x;
    for (int i = t; i < BSIZE * 16; i += 1024) al[i] = 0.f;
    __syncthreads();
    const int cnt = min(gcnt[b * CSTRIDE], CAP);
    const long long* p = ep + (size_t)b * CAP;
    const int eo = t >> 4, j = t & 15;   // 64 edge-groups x 16 features
    for (int e = eo; e < cnt; e += 64) {
        long long rec = p[e];                         // 16 lanes same addr -> broadcast
        unsigned int meta = (unsigned int)rec;
        float nv = __int_as_float((int)(rec >> 32));
        int s = meta & NSRC_MASK;
        int dl = meta >> 17;
        atomicAdd(&al[dl * 16 + j], z[s * 16 + j] * nv);
    }
    __syncthreads();
    for (int i = t; i < BSIZE * 16; i += 1024) {
        int node = (b << BSHIFT) + (i >> 4);
        if (node < n) {
            float di = dis[node];
            int jj = i & 15;
            acc[node * 16 + jj] = z[node * 16 + jj] * di * di + al[i];
        }
    }
}

// ---- aggregation FO=1 + final relu+bias+mean, fused ----
__global__ __launch_bounds__(BLK) void k_agg1(const long long* __restrict__ ep, const int* __restrict__ gcnt,
                                              const float* __restrict__ dis, const float* __restrict__ z1,
                                              const float* __restrict__ b4, float* __restrict__ out, int n) {
    __shared__ float al[BSIZE];
    const int b = blockIdx.x, t = threadIdx.x;
    al[t] = 0.f;
    __syncthreads();
    const int cnt = min(gcnt[b * CSTRIDE], CAP);
    const long long* p = ep + (size_t)b * CAP;
    for (int e = t; e < cnt; e += BLK) {
        long long rec = p[e];
        unsigned int meta = (unsigned int)rec;
        float nv = __int_as_float((int)(rec >> 32));
        atomicAdd(&al[meta >> 17], z1[meta & NSRC_MASK] * nv);
    }
    __syncthreads();
    int node = (b << BSHIFT) + t;
    float v = 0.f;
    if (node < n) {
        float di = dis[node];
        v = relu_(z1[node] * di * di + al[t] + b4[0]);
    }
#pragma unroll
    for (int o = 32; o > 0; o >>= 1) v += __shfl_down(v, o, 64);
    __shared__ float wsum[BLK / 64];
    if ((t & 63) == 0) wsum[t >> 6] = v;
    __syncthreads();
    if (t == 0) {
        float s = 0.f;
#pragma unroll
        for (int k = 0; k < BLK / 64; ++k) s += wsum[k];
        atomicAdd(out, s / (float)n);
    }
}

static inline size_t align_up(size_t x) { return (x + 255) & ~(size_t)255; }

extern "C" void kernel_launch(void* const* d_in, const int* in_sizes, int n_in,
                              void* d_out, int out_size, void* d_ws, size_t ws_size,
                              hipStream_t stream) {
    const float* vf  = (const float*)d_in[0];   // [N,128]
    const int*   edg = (const int*)d_in[1];     // [2,E] int32
    const float* w   = (const float*)d_in[2];   // [E]
    const float* W1  = (const float*)d_in[3];
    const float* b1  = (const float*)d_in[4];
    const float* W2  = (const float*)d_in[5];
    const float* b2  = (const float*)d_in[6];
    const float* W3  = (const float*)d_in[7];
    const float* b3  = (const float*)d_in[8];
    const float* W4  = (const float*)d_in[9];
    const float* b4  = (const float*)d_in[10];
    float* out = (float*)d_out;

    const int n = in_sizes[0] / 128;   // 100000
    const int E = in_sizes[2];         // 6400000
    const int* src = edg;
    const int* dst = edg + E;
    const int nbuck = (n + BSIZE - 1) >> BSHIFT;   // 391

    char* ws = (char*)d_ws;
    size_t off = 0;
    int*       gcnt = (int*)(ws + off);       off += align_up((size_t)nbuck * CSTRIDE * 4);
    float*     dis  = (float*)(ws + off);     off += align_up((size_t)n * 4);
    long long* ep   = (long long*)(ws + off); off += align_up((size_t)nbuck * CAP * 8);
    float*     z    = (float*)(ws + off);     off += align_up((size_t)n * 16 * 4);
    float*     acc  = (float*)(ws + off);     off += align_up((size_t)n * 16 * 4);
    float*     z1   = z;   // layer-4 dense output aliases z (only n floats used)
    (void)ws_size;

    const int gZ = (nbuck * CSTRIDE + BLK - 1) / BLK;
    const int gB = (E + CHUNK - 1) / CHUNK;              // 782
    const int gD16 = (n + (BLK / 16) - 1) / (BLK / 16);  // dense FO=16
    const int gN = (n + BLK - 1) / BLK;

    k_zero<<<gZ, BLK, 0, stream>>>(gcnt, out, nbuck * CSTRIDE);
    k_bucket<<<gB, BLK, 0, stream>>>(src, dst, w, gcnt, ep, E, nbuck);
    k_degdis<<<nbuck, BLK, 0, stream>>>(ep, gcnt, dis, n);
    k_norm<<<nbuck, BLK, 0, stream>>>(ep, gcnt, dis, n);

    // layer 1: 128 -> 16
    k_dense<128, 16, false><<<gD16, BLK, 0, stream>>>(vf, W1, nullptr, z, n);
    k_agg16<<<nbuck, 1024, 0, stream>>>(ep, gcnt, dis, z, acc, n);
    // layer 2: 16 -> 16
    k_dense<16, 16, true><<<gD16, BLK, 0, stream>>>(acc, W2, b1, z, n);
    k_agg16<<<nbuck, 1024, 0, stream>>>(ep, gcnt, dis, z, acc, n);
    // layer 3: 16 -> 16
    k_dense<16, 16, true><<<gD16, BLK, 0, stream>>>(acc, W3, b2, z, n);
    k_agg16<<<nbuck, 1024, 0, stream>>>(ep, gcnt, dis, z, acc, n);
    // layer 4: 16 -> 1 + aggregation + relu+bias+mean (fused)
    k_dense<16, 1, true><<<gN, BLK, 0, stream>>>(acc, W4, b3, z1, n);
    k_agg1<<<nbuck, BLK, 0, stream>>>(ep, gcnt, dis, z1, b4, out, n);
}